// Round 13
// baseline (540.898 us; speedup 1.0000x reference)
//
#include <hip/hip_runtime.h>
#include <math.h>

// KNN (L2 top-32) + cosine re-rank, MI355X.
// P0 : fused row sum-of-squares (exact fp32) + fp32->bf16(hi,RTN) table write.
// P1 : 1-pass bf16 MFMA distance GEMM (32x32x16), 32q x 256c tiles, KC=32.
//      4-deep ring of C slices (3 in flight, vmcnt(6) steady, exact counts:
//      NO other VMEM in the loop; c2 double-buffered in regs, retired by the
//      ring waits). Q resident in LDS (staged once, swizzled). Wave-private
//      barrier-free main loop; 2 barriers per tile (dl exchange). 8 waves/CU.
//      Selection: per-lane register top-5 (pure VALU), b128 dl scan,
//      end-of-chunk pivot+compact+rank -> per-chunk noisy top-32 (d^2 keys).
// P2 : merge 8x32 -> noisy top-64 -> EXACT fp32 rescore -> exact top-32 -> cosine.
// Fallback (small ws): R4's in-kernel-conversion 3-pass kernel (proven).

#define D       512
#define KSEL    32
#define NSELMX  64
#define NCF     8      // chunks == #XCDs
#define TOPL    5
#define CEPS    1e-8f
#define INF     __builtin_inff()

// fast-path phase-1 geometry
#define MTF     32
#define NTF     256
#define KCF     32
#define NTHF    512

// fallback geometry (R4 kernel, unchanged)
#define MT      64
#define NT      512
#define KC      64
#define NTH     512

using s16x8  = __attribute__((ext_vector_type(8)))  short;
using f32x16 = __attribute__((ext_vector_type(16))) float;

__device__ __forceinline__ void async16(const void* g, void* s) {
  __builtin_amdgcn_global_load_lds(
      (const __attribute__((address_space(1))) unsigned int*)g,
      (__attribute__((address_space(3))) unsigned int*)s, 16, 0, 0);
}

// LDS-only barrier (no vmcnt drain)
#define BARL() do { asm volatile("s_waitcnt lgkmcnt(0)" ::: "memory"); \
                    __builtin_amdgcn_s_barrier();                      \
                    asm volatile("" ::: "memory"); } while (0)

// two fp32 -> packed bf16 pair (RTN)
__device__ __forceinline__ unsigned int bfhi2(float x0, float x1) {
  unsigned int u0 = __float_as_uint(x0), u1 = __float_as_uint(x1);
  u0 = (u0 + 0x7fffu + ((u0 >> 16) & 1u)) >> 16;
  u1 = (u1 + 0x7fffu + ((u1 >> 16) & 1u)) & 0xffff0000u;
  return u0 | u1;
}

// ---------------- P0 (fast): fused sumsq + bf16 conversion ----------------
__global__ __launch_bounds__(256) void sumsq_cvt_kernel(
    const float* __restrict__ C, const float* __restrict__ Q,
    float* __restrict__ c2, float* __restrict__ q2,
    unsigned short* __restrict__ Cb, unsigned short* __restrict__ Qb,
    int n2, int n1)
{
  int wid  = threadIdx.x >> 6;
  int lane = threadIdx.x & 63;
  int row  = blockIdx.x * 4 + wid;
  const float* src; float* dst; unsigned short* bdst;
  if (row < n2) { src = C + (size_t)row * D; dst = c2 + row; bdst = Cb + (size_t)row * D; }
  else {
    int r = row - n2; if (r >= n1) return;
    src = Q + (size_t)r * D; dst = q2 + r; bdst = Qb + (size_t)r * D;
  }
  const float4* s4 = (const float4*)src;
  float4 a = s4[2*lane], b = s4[2*lane + 1];
  float s = a.x*a.x + a.y*a.y + a.z*a.z + a.w*a.w
          + b.x*b.x + b.y*b.y + b.z*b.z + b.w*b.w;
  int4 h;
  h.x = (int)bfhi2(a.x, a.y); h.y = (int)bfhi2(a.z, a.w);
  h.z = (int)bfhi2(b.x, b.y); h.w = (int)bfhi2(b.z, b.w);
  *(int4*)(bdst + 8*lane) = h;
  #pragma unroll
  for (int o = 32; o > 0; o >>= 1) s += __shfl_down(s, o, 64);
  if (lane == 0) *dst = s;
}

// ---------------- P0 (fallback): row sum-of-squares only ----------------
__global__ __launch_bounds__(256) void rows_sumsq_kernel(
    const float* __restrict__ C, const float* __restrict__ Q,
    float* __restrict__ c2, float* __restrict__ q2, int n2, int n1)
{
  int wid  = threadIdx.x >> 6;
  int lane = threadIdx.x & 63;
  int row  = blockIdx.x * 4 + wid;
  const float* src; float* dst;
  if (row < n2) { src = C + (size_t)row * D; dst = c2 + row; }
  else { int r = row - n2; if (r >= n1) return; src = Q + (size_t)r * D; dst = q2 + r; }
  const float4* s4 = (const float4*)src;
  float4 a = s4[lane], b = s4[lane + 64];
  float s = a.x*a.x + a.y*a.y + a.z*a.z + a.w*a.w
          + b.x*b.x + b.y*b.y + b.z*b.z + b.w*b.w;
  #pragma unroll
  for (int o = 32; o > 0; o >>= 1) s += __shfl_down(s, o, 64);
  if (lane == 0) *dst = s;
}

// lexicographic max of (d,i) over lanes 0..31 (fallback kernel only)
__device__ inline void worst_reduce(float dIn, int iIn, float& wd, int& wi) {
  float dd = dIn; int ii = iIn;
  #pragma unroll
  for (int o = 1; o <= 16; o <<= 1) {
    float dp = __shfl_xor(dd, o, 64);
    int   ip = __shfl_xor(ii, o, 64);
    bool take = (dp > dd) || (dp == dd && ip > ii);
    dd = take ? dp : dd; ii = take ? ip : ii;
  }
  wd = __shfl(dd, 0, 64); wi = __shfl(ii, 0, 64);
}

// fp32 -> (bf16_hi, bf16_lo) split (fallback kernel only)
__device__ inline void cvt8(const float4 a, const float4 b, int4& hi, int4& lo) {
  float x[8] = {a.x, a.y, a.z, a.w, b.x, b.y, b.z, b.w};
  unsigned int hw[8], lw[8];
  #pragma unroll
  for (int j = 0; j < 8; ++j) {
    unsigned int ux = __float_as_uint(x[j]);
    unsigned int rh = (ux + 0x7fffu + ((ux >> 16) & 1u)) & 0xffff0000u;
    float rl = x[j] - __uint_as_float(rh);
    unsigned int ul = __float_as_uint(rl);
    hw[j] = rh >> 16;
    lw[j] = (ul + 0x7fffu + ((ul >> 16) & 1u)) >> 16;
  }
  hi = make_int4((int)(hw[0]|(hw[1]<<16)), (int)(hw[2]|(hw[3]<<16)),
                 (int)(hw[4]|(hw[5]<<16)), (int)(hw[6]|(hw[7]<<16)));
  lo = make_int4((int)(lw[0]|(lw[1]<<16)), (int)(lw[2]|(lw[3]<<16)),
                 (int)(lw[4]|(lw[5]<<16)), (int)(lw[6]|(lw[7]<<16)));
}

// ---------------- Phase 1 (fast): ring-4 deep-pipelined bf16 MFMA ----------------
// LDS (128KB): qs [32][512] swz 32K [0,32K) | ring 4x16K [32K,96K) | dl [32][256] 32K [96K,128K)
// end-of-chunk sel buffer reuses [0,32K): 512 u64/wave.
__global__ __launch_bounds__(NTHF, 2) void knn_phase1_bf_kernel(
    const unsigned short* __restrict__ Qb, const unsigned short* __restrict__ Cb,
    const float* __restrict__ q2g, const float* __restrict__ c2g,
    float* __restrict__ tkd, int* __restrict__ tki,
    int n1, int n2, int chunk, int nc)
{
  extern __shared__ char smem[];
  unsigned short* qs = (unsigned short*)smem;       // [32][512] swizzled
  char* ringb = smem + 32768;                       // 4 x 16KB
  float* dl   = (float*)(smem + 98304);             // [32][256]

  const int tid  = threadIdx.x;
  const int w    = tid >> 6;       // wave 0..7
  const int l    = tid & 63;
  const int l31  = l & 31;
  const int half = l >> 5;
  const int bid     = blockIdx.x;
  const int chunkid = bid & (NCF - 1);   // XCD chunk-affinity
  const int mbase   = (bid >> 3) * MTF;
  const int cbase0  = chunkid * chunk;
  const int cend    = min(cbase0 + chunk, n2);

  // wave w owns query rows mbase + w*4 + [0,4)
  float q2w[4];
  #pragma unroll
  for (int g = 0; g < 4; ++g) q2w[g] = q2g[min(mbase + w*4 + g, n1 - 1)];

  unsigned long long vv[4][TOPL];
  #pragma unroll
  for (int g = 0; g < 4; ++g)
    #pragma unroll
    for (int t = 0; t < TOPL; ++t) vv[g][t] = 0xffffffffffffffffULL;

  // c2 double-buffer: tile 0's c2 loaded FIRST (oldest in vm queue -> retired
  // by the prologue vmcnt(6)); each tile prefetches the next tile's c2.
  float4 c2cur = *(const float4*)(c2g + cbase0 + 4*l);
  float4 c2nxt = c2cur;

  // ---- prologue: stage Q once (swizzled: phys unit u holds global unit u^(row&7)) ----
  #pragma unroll
  for (int g = 0; g < 4; ++g) {
    int rho = w*4 + g;
    int gq  = min(mbase + rho, n1 - 1);
    const unsigned short* src = Qb + (size_t)gq * D + (size_t)((l ^ (rho & 7)) * 8);
    unsigned short* dst = qs + rho * 512;            // wave-uniform base; lane*16B implicit
    async16(src, dst);
  }

  // C stage: slice s4 = (tile s4>>4, kb s4&15); wave stripe rows w*32+[0,32)
  const int srcu = (l & 3) ^ ((l >> 3) & 3);         // pre-swizzled source unit
  auto STAGE = [&](int slot, int s4) {
    int t4 = s4 >> 4, kb4 = s4 & 15;
    int rowg = cbase0 + t4*NTF + w*32;
    #pragma unroll
    for (int i = 0; i < 2; ++i) {
      int gr = rowg + i*16 + (l >> 2);               // padded Cb: may overrun cend
      const unsigned short* src = Cb + (size_t)gr * D + kb4*KCF + srcu*8;
      unsigned short* dst = (unsigned short*)(ringb + slot*16384) + (w*32 + i*16)*32;
      async16(src, dst);
    }
  };

  f32x16 zf;
  #pragma unroll
  for (int e = 0; e < 16; ++e) zf[e] = 0.f;

  const int nst   = (cend - cbase0 + NTF - 1) / NTF;
  const int total = nst * 16;
  STAGE(0,0); STAGE(1,1); STAGE(2,2); STAGE(3,3);
  // retire c2cur(1) + Q(4) + slice0(2): 13 outstanding -> 6
  asm volatile("s_waitcnt vmcnt(6)" ::: "memory");
  __builtin_amdgcn_s_barrier();                      // all waves' Q visible

  const unsigned short* qrow = qs + l31 * 512;
  f32x16 acc = zf;

  for (int nt = 0; nt < nst; ++nt) {
    const int cbase = cbase0 + nt * NTF;

    #pragma unroll
    for (int kb = 0; kb < 16; ++kb) {
      const int s   = nt*16 + kb;
      const int rem = total - 1 - s;
      if (rem > 2)       asm volatile("s_waitcnt vmcnt(6)" ::: "memory");
      else if (rem == 2) asm volatile("s_waitcnt vmcnt(4)" ::: "memory");
      else if (rem == 1) asm volatile("s_waitcnt vmcnt(2)" ::: "memory");
      else               asm volatile("s_waitcnt vmcnt(0)" ::: "memory");

      if (kb == 0)   // prefetch next tile's c2 (retires under later ring waits)
        c2nxt = *(const float4*)(c2g + cbase + NTF + 4*l);

      const unsigned short* cb_ =
          (const unsigned short*)(ringb + (s & 3)*16384) + (w*32 + l31)*32;
      #pragma unroll
      for (int ks = 0; ks < 2; ++ks) {
        int qu = ((kb << 2) + (ks << 1) + half) ^ (l31 & 7);
        s16x8 qf = *(const s16x8*)(qrow + qu*8);
        int p  = ((ks << 1) + half) ^ ((l31 >> 1) & 3);
        s16x8 cf = *(const s16x8*)(cb_ + p*8);
        acc = __builtin_amdgcn_mfma_f32_32x32x16_bf16(qf, cf, acc, 0, 0, 0);
      }
      if (s + 4 < total) {
        asm volatile("s_waitcnt lgkmcnt(0)" ::: "memory");   // my reads of slot done
        STAGE(s & 3, s + 4);
      }
    }

    // ---- tile epilogue: dl exchange + per-lane filter (2 barriers) ----
    #pragma unroll
    for (int r = 0; r < 16; ++r) {
      int row = (r & 3) + 8*(r >> 2) + 4*half;       // verified 32x32 C layout
      dl[row*NTF + w*32 + l31] = acc[r];             // raw dot
    }
    BARL();
    {
      float c2s[4] = {c2cur.x, c2cur.y, c2cur.z, c2cur.w};
      #pragma unroll
      for (int g = 0; g < 4; ++g) {
        const float q2u = q2w[g];
        float4 sv4 = *((const float4*)(dl + (w*4 + g)*NTF) + l);
        float svs[4] = {sv4.x, sv4.y, sv4.z, sv4.w};
        #pragma unroll
        for (int jj = 0; jj < 4; ++jj) {
          int ci = cbase + 4*l + jj;
          if (ci < cend) {
            float d2v = fmaxf(q2u + c2s[jj] - 2.f*svs[jj], 0.f);
            unsigned long long e =
                ((unsigned long long)__float_as_uint(d2v) << 32) | (unsigned int)ci;
            if (e < vv[g][TOPL-1]) {
              vv[g][TOPL-1] = e;
              #pragma unroll
              for (int t = TOPL-1; t > 0; --t) {
                unsigned long long lo = vv[g][t-1] < vv[g][t] ? vv[g][t-1] : vv[g][t];
                unsigned long long hi = vv[g][t-1] < vv[g][t] ? vv[g][t]   : vv[g][t-1];
                vv[g][t-1] = lo; vv[g][t] = hi;
              }
            }
          }
        }
      }
    }
    BARL();
    acc = zf;
    c2cur = c2nxt;
  }

  // ---- end-of-chunk selection: pivot + compact + rank (per wave, 4 lists) ----
  unsigned long long* sel = (unsigned long long*)smem + (size_t)w * 512;
  const unsigned long long mlt = (l == 0) ? 0ull : ((~0ull) >> (64 - l));
  __syncthreads();   // everyone past main loop before qs/ring reuse
  #pragma unroll
  for (int g = 0; g < 4; ++g) {
    unsigned int pk = (unsigned int)(vv[g][0] >> 32);
    #pragma unroll
    for (int o = 1; o < 64; o <<= 1) {
      unsigned int other = (unsigned int)__shfl_xor((int)pk, o, 64);
      pk = (other > pk) ? other : pk;
    }
    int cnt = 0;
    #pragma unroll
    for (int t = 0; t < TOPL; ++t) cnt += ((unsigned int)(vv[g][t] >> 32) <= pk) ? 1 : 0;
    unsigned long long b0 = __ballot(cnt & 1);
    unsigned long long b1 = __ballot(cnt & 2);
    unsigned long long b2 = __ballot(cnt & 4);
    int pre = __popcll(b0 & mlt) + 2*__popcll(b1 & mlt) + 4*__popcll(b2 & mlt);
    int Ns  = __popcll(b0) + 2*__popcll(b1) + 4*__popcll(b2);
    #pragma unroll
    for (int t = 0; t < TOPL; ++t)
      if (t < cnt) sel[pre + t] = vv[g][t];
    asm volatile("s_waitcnt lgkmcnt(0)" ::: "memory");
    __builtin_amdgcn_sched_barrier(0);
    int rk[TOPL];
    #pragma unroll
    for (int t = 0; t < TOPL; ++t) rk[t] = 0;
    for (int j = 0; j < Ns; ++j) {
      unsigned long long e = sel[j];
      #pragma unroll
      for (int t = 0; t < TOPL; ++t) rk[t] += (e < vv[g][t]) ? 1 : 0;
    }
    int gq = mbase + w*4 + g;
    if (gq < n1) {
      #pragma unroll
      for (int t = 0; t < TOPL; ++t)
        if (t < cnt && rk[t] < KSEL) {
          size_t o = ((size_t)gq * nc + chunkid) * KSEL + rk[t];
          tkd[o] = __uint_as_float((unsigned int)(vv[g][t] >> 32));
          tki[o] = (int)(unsigned int)(vv[g][t] & 0xffffffffu);
        }
    }
  }
}

// ---------------- Phase 1 (fallback): R4 in-kernel-conversion 3-pass ----------------
__global__ __launch_bounds__(NTH) void knn_phase1_cvt_kernel(
    const float* __restrict__ Q, const float* __restrict__ C,
    const float* __restrict__ q2g, const float* __restrict__ c2g,
    float* __restrict__ tkd, int* __restrict__ tki,
    int n1, int n2, int chunk, int nc)
{
  extern __shared__ char smem[];
  unsigned short* qh = (unsigned short*)smem;
  unsigned short* ql = qh + 64*64;
  unsigned short* ch = ql + 64*64;
  unsigned short* cl = ch + 512*64;
  float* dl = (float*)(smem + 147456);

  const int tid  = threadIdx.x;
  const int w    = tid >> 6;
  const int l    = tid & 63;
  const int l31  = l & 31;
  const int half = l >> 5;
  const int mbase   = blockIdx.x * MT;
  const int chunkid = blockIdx.y;
  const int cbase0  = chunkid * chunk;
  const int cend    = min(cbase0 + chunk, n2);

  float q2w[8];
  #pragma unroll
  for (int g = 0; g < 8; ++g) q2w[g] = q2g[min(mbase + g*8 + w, n1 - 1)];

  float listd[8]; int listi[8]; float wd4[8]; int wi4[8];
  #pragma unroll
  for (int g = 0; g < 8; ++g) { listd[g]=INF; listi[g]=0x7fffffff; wd4[g]=INF; wi4[g]=0x7fffffff; }

  const int srow = tid >> 3;
  const int sk8  = (tid & 7) * 8;
  const int su   = (tid & 7);

  float4 cva[8][2], qva[2];
  auto LOADR = [&](int kb, int cb) {
    {
      int gr = min(mbase + srow, n1 - 1);
      const float4* p = (const float4*)(Q + (size_t)gr * D + kb*KC + sk8);
      qva[0] = p[0]; qva[1] = p[1];
    }
    #pragma unroll
    for (int r = 0; r < 8; ++r) {
      int gn = cb + srow + 64*r;
      if (gn < cend) {
        const float4* p = (const float4*)(C + (size_t)gn * D + kb*KC + sk8);
        cva[r][0] = p[0]; cva[r][1] = p[1];
      } else {
        cva[r][0] = make_float4(0.f,0.f,0.f,0.f);
        cva[r][1] = make_float4(0.f,0.f,0.f,0.f);
      }
    }
  };
  auto STORE = [&]() {
    int4 hi, lo;
    {
      int idx = srow*64 + (su ^ (srow & 7))*8;
      cvt8(qva[0], qva[1], hi, lo);
      *(int4*)(qh + idx) = hi; *(int4*)(ql + idx) = lo;
    }
    #pragma unroll
    for (int r = 0; r < 8; ++r) {
      int row = srow + 64*r;
      int idx = row*64 + (su ^ (row & 7))*8;
      cvt8(cva[r][0], cva[r][1], hi, lo);
      *(int4*)(ch + idx) = hi; *(int4*)(cl + idx) = lo;
    }
  };

  f32x16 zf;
  #pragma unroll
  for (int e = 0; e < 16; ++e) zf[e] = 0.f;

  const int nsteps = (cend - cbase0 + NT - 1) / NT;
  LOADR(0, cbase0);

  for (int nt = 0; nt < nsteps; ++nt) {
    const int cbase = cbase0 + nt * NT;
    f32x16 acc[2][2];
    #pragma unroll
    for (int rt = 0; rt < 2; ++rt)
      #pragma unroll
      for (int ct = 0; ct < 2; ++ct) acc[rt][ct] = zf;

    for (int kb = 0; kb < D/KC; ++kb) {
      __syncthreads();
      STORE();
      __syncthreads();
      if (kb + 1 < D/KC)        LOADR(kb + 1, cbase);
      else if (nt + 1 < nsteps) LOADR(0, cbase + NT);

      #pragma unroll
      for (int ks = 0; ks < 4; ++ks) {
        const int u = 2*ks + half;
        s16x8 qf[2][2], cf[2][2];
        #pragma unroll
        for (int rt = 0; rt < 2; ++rt) {
          int r = rt*32 + l31;
          int idx = r*64 + (u ^ (r & 7))*8;
          qf[rt][0] = *(const s16x8*)(qh + idx);
          qf[rt][1] = *(const s16x8*)(ql + idx);
        }
        #pragma unroll
        for (int ct = 0; ct < 2; ++ct) {
          int c = w*64 + ct*32 + l31;
          int idx = c*64 + (u ^ (c & 7))*8;
          cf[ct][0] = *(const s16x8*)(ch + idx);
          cf[ct][1] = *(const s16x8*)(cl + idx);
        }
        #pragma unroll
        for (int rt = 0; rt < 2; ++rt)
          #pragma unroll
          for (int ct = 0; ct < 2; ++ct) {
            acc[rt][ct] = __builtin_amdgcn_mfma_f32_32x32x16_bf16(qf[rt][0], cf[ct][0], acc[rt][ct], 0, 0, 0);
            acc[rt][ct] = __builtin_amdgcn_mfma_f32_32x32x16_bf16(qf[rt][0], cf[ct][1], acc[rt][ct], 0, 0, 0);
            acc[rt][ct] = __builtin_amdgcn_mfma_f32_32x32x16_bf16(qf[rt][1], cf[ct][0], acc[rt][ct], 0, 0, 0);
          }
      }
    }

    float c2v[2]; int vld[2];
    #pragma unroll
    for (int ct = 0; ct < 2; ++ct) {
      int gc = cbase + w*64 + ct*32 + l31;
      vld[ct] = (gc < cend);
      c2v[ct] = vld[ct] ? c2g[gc] : 0.f;
    }
    #pragma unroll
    for (int g = 0; g < 8; ++g) {
      const int rt = g >> 2, qq = g & 3;
      #pragma unroll
      for (int jj = 0; jj < 4; ++jj)
        #pragma unroll
        for (int ct = 0; ct < 2; ++ct) {
          float a = acc[rt][ct][4*qq + jj];
          float s = c2v[ct] - 2.f * a;
          dl[(4*half + jj)*512 + w*64 + ct*32 + l31] = vld[ct] ? s : INF;
        }
      __syncthreads();
      const float q2u = q2w[g];
      #pragma unroll
      for (int j2 = 0; j2 < 8; ++j2) {
        float sv = dl[w*512 + l + 64*j2];
        float dv = sqrtf(fmaxf(q2u + sv, 0.f));
        unsigned long long mask = __ballot(dv < wd4[g]);
        while (mask) {
          int L = __ffsll(mask) - 1; mask &= mask - 1;
          float dnew = __shfl(dv, L, 64);
          int ci = cbase + 64*j2 + L;
          if ((dnew < wd4[g]) || (dnew == wd4[g] && ci < wi4[g])) {
            bool isw = (l < 32) && (listd[g] == wd4[g]) && (listi[g] == wi4[g]);
            int wl = __ffsll(__ballot(isw)) - 1;
            if (l == wl) { listd[g] = dnew; listi[g] = ci; }
            worst_reduce((l < 32) ? listd[g] : -1.f,
                         (l < 32) ? listi[g] : -1, wd4[g], wi4[g]);
          }
        }
      }
      __syncthreads();
    }
  }

  #pragma unroll
  for (int g = 0; g < 8; ++g) {
    int gq = mbase + g*8 + w;
    float d = listd[g]; int i = listi[g];
    int rank = 0;
    #pragma unroll
    for (int j = 0; j < KSEL; ++j) {
      float dj = __shfl(listd[g], j, 64);
      int   ij = __shfl(listi[g], j, 64);
      rank += (dj < d) || (dj == d && ij < i);
    }
    if (l < 32 && gq < n1) {
      size_t o = ((size_t)gq * nc + chunkid) * KSEL + rank;
      tkd[o] = d; tki[o] = i;
    }
  }
}

// ---------------- Phase 2: merge + exact rescore + cosine ----------------
__global__ __launch_bounds__(256) void knn_phase2_kernel(
    const float* __restrict__ Q0, const float* __restrict__ Q1,
    const float* __restrict__ C0, const float* __restrict__ C1,
    const float* __restrict__ q2g, const float* __restrict__ c2g,
    const float* __restrict__ tkd, const int* __restrict__ tki,
    float* __restrict__ out, int n1, int n2, int nc)
{
  __shared__ float q0s[D], q1s[D];
  __shared__ float pd[256]; __shared__ int pi[256];
  __shared__ float nd[NSELMX]; __shared__ int ni[NSELMX];
  __shared__ float de[NSELMX];
  __shared__ int   fi[KSEL];
  __shared__ float cosj[KSEL];
  __shared__ float red0[4], red1[4], qn[2];

  const int q = blockIdx.x, tid = threadIdx.x;
  const int npool = nc * KSEL;
  const int nsel  = (NSELMX < npool) ? NSELMX : npool;

  if (tid < 128) ((float4*)q0s)[tid] = ((const float4*)(Q0 + (size_t)q*D))[tid];
  else           ((float4*)q1s)[tid-128] = ((const float4*)(Q1 + (size_t)q*D))[tid-128];
  if (tid < npool) { pd[tid] = tkd[(size_t)q*npool + tid]; pi[tid] = tki[(size_t)q*npool + tid]; }
  __syncthreads();

  float a0 = q0s[tid], b0 = q0s[tid+256], a1 = q1s[tid], b1 = q1s[tid+256];
  float s0 = a0*a0 + b0*b0, s1 = a1*a1 + b1*b1;
  #pragma unroll
  for (int o = 32; o > 0; o >>= 1) { s0 += __shfl_down(s0, o, 64); s1 += __shfl_down(s1, o, 64); }
  int lane = tid & 63, wid = tid >> 6;
  if (lane == 0) { red0[wid] = s0; red1[wid] = s1; }

  if (tid < npool) {
    float dm = pd[tid]; int im = pi[tid]; int rank = 0;
    for (int j = 0; j < npool; ++j) {
      float dj = pd[j]; int ij = pi[j];
      rank += (dj < dm) || (dj == dm && ij < im);
    }
    if (rank < nsel) { nd[rank] = dm; ni[rank] = im; }
  }
  __syncthreads();
  if (tid == 0) {
    qn[0] = fmaxf(sqrtf(red0[0]+red0[1]+red0[2]+red0[3]), CEPS);
    qn[1] = fmaxf(sqrtf(red1[0]+red1[1]+red1[2]+red1[3]), CEPS);
  }

  const float q2q = q2g[q];
  const int ll = tid & 7;
  for (int base = 0; base < NSELMX; base += 32) {
    int g = base + (tid >> 3);
    if (g < nsel) {
      int ix = ni[g];
      bool okx = (ix >= 0 && ix < n2);
      int ixc = okx ? ix : 0;
      const float4* r0  = (const float4*)(C0 + (size_t)ixc * D);
      const float4* q04 = (const float4*)q0s;
      float dot = 0.f;
      #pragma unroll
      for (int r = 0; r < 16; ++r) {
        float4 v = r0[r*8 + ll], u = q04[r*8 + ll];
        dot = fmaf(v.x,u.x, fmaf(v.y,u.y, fmaf(v.z,u.z, fmaf(v.w,u.w, dot))));
      }
      #pragma unroll
      for (int o = 4; o > 0; o >>= 1) dot += __shfl_xor(dot, o, 64);
      if (ll == 0) de[g] = okx ? sqrtf(fmaxf(q2q + c2g[ixc] - 2.f*dot, 0.f)) : INF;
    }
  }
  __syncthreads();

  if (tid < nsel) {
    float dm = de[tid]; int im = ni[tid]; int rank = 0;
    for (int j = 0; j < nsel; ++j) {
      float dj = de[j]; int ij = ni[j];
      rank += (dj < dm) || (dj == dm && ij < im);
    }
    if (rank < KSEL) fi[rank] = im;
  }
  __syncthreads();

  const int g = tid >> 3;
  int ix = fi[g];
  ix = (ix >= 0 && ix < n2) ? ix : 0;
  const float4* r0  = (const float4*)(C0 + (size_t)ix * D);
  const float4* r1  = (const float4*)(C1 + (size_t)ix * D);
  const float4* q04 = (const float4*)q0s;
  const float4* q14 = (const float4*)q1s;
  float dot0 = 0.f, nn0 = 0.f, dot1 = 0.f, nn1 = 0.f;
  #pragma unroll
  for (int r = 0; r < 16; ++r) {
    int e4 = r*8 + ll;
    float4 v0 = r0[e4], qv0 = q04[e4];
    dot0 = fmaf(v0.x,qv0.x, fmaf(v0.y,qv0.y, fmaf(v0.z,qv0.z, fmaf(v0.w,qv0.w, dot0))));
    nn0  = fmaf(v0.x,v0.x,  fmaf(v0.y,v0.y,  fmaf(v0.z,v0.z,  fmaf(v0.w,v0.w,  nn0))));
    float4 v1 = r1[e4], qv1 = q14[e4];
    dot1 = fmaf(v1.x,qv1.x, fmaf(v1.y,qv1.y, fmaf(v1.z,qv1.z, fmaf(v1.w,qv1.w, dot1))));
    nn1  = fmaf(v1.x,v1.x,  fmaf(v1.y,v1.y,  fmaf(v1.z,v1.z,  fmaf(v1.w,v1.w,  nn1))));
  }
  #pragma unroll
  for (int o = 4; o > 0; o >>= 1) {
    dot0 += __shfl_xor(dot0, o, 64); nn0 += __shfl_xor(nn0, o, 64);
    dot1 += __shfl_xor(dot1, o, 64); nn1 += __shfl_xor(nn1, o, 64);
  }
  if (ll == 0) {
    float c0 = dot0 / (fmaxf(sqrtf(nn0), CEPS) * qn[0]);
    float c1 = dot1 / (fmaxf(sqrtf(nn1), CEPS) * qn[1]);
    float cv = (c0 > c1) ? c0 : c1;
    out[(size_t)q * KSEL + g] = cv;
    cosj[g] = cv;
  }
  __syncthreads();
  if (tid == 0) {
    float s = 0.f;
    #pragma unroll
    for (int j = 0; j < KSEL; ++j) s += cosj[j];
    out[(size_t)n1 * KSEL + q] = s * (1.f / KSEL);
  }
}

// ---------------- launch ----------------
extern "C" void kernel_launch(void* const* d_in, const int* in_sizes, int n_in,
                              void* d_out, int out_size, void* d_ws, size_t ws_size,
                              hipStream_t stream)
{
  const float* Q0 = (const float*)d_in[0];
  const float* Q1 = (const float*)d_in[1];
  const float* C0 = (const float*)d_in[2];
  const float* C1 = (const float*)d_in[3];
  const int n1 = in_sizes[0] / D;   // 2048
  const int n2 = in_sizes[2] / D;   // 50000
  float* out = (float*)d_out;
  if (n1 <= 0 || n2 <= 0) return;

  char* wsb = (char*)d_ws;
  size_t c2n = ((size_t)n2 + 127) & ~(size_t)127;
  size_t q2n = ((size_t)n1 + 127) & ~(size_t)127;

  size_t off_c2  = 0;
  size_t off_q2  = off_c2 + c2n*4;
  size_t off_tkd = off_q2 + q2n*4;
  size_t off_tki = off_tkd + (size_t)n1*NCF*KSEL*4;
  size_t off_cb  = (off_tki + (size_t)n1*NCF*KSEL*4 + 255) & ~(size_t)255;
  size_t off_qb  = off_cb + ((size_t)n2 + 512)*D*2;
  size_t need    = off_qb + (size_t)n1*D*2;
  bool fast = (ws_size >= need);

  if (fast) {
    float* c2  = (float*)(wsb + off_c2);
    float* q2  = (float*)(wsb + off_q2);
    float* tkd = (float*)(wsb + off_tkd);
    int*   tki = (int*)(wsb + off_tki);
    unsigned short* Cb = (unsigned short*)(wsb + off_cb);
    unsigned short* Qb = (unsigned short*)(wsb + off_qb);

    sumsq_cvt_kernel<<<(n2 + n1 + 3)/4, 256, 0, stream>>>(C0, Q0, c2, q2, Cb, Qb, n2, n1);

    const int chunk  = (n2 + NCF - 1) / NCF;
    const int mtiles = (n1 + MTF - 1) / MTF;
    (void)hipFuncSetAttribute((const void*)knn_phase1_bf_kernel,
                              hipFuncAttributeMaxDynamicSharedMemorySize, 131072);
    knn_phase1_bf_kernel<<<mtiles * NCF, NTHF, 131072, stream>>>(
        Qb, Cb, q2, c2, tkd, tki, n1, n2, chunk, NCF);
    knn_phase2_kernel<<<n1, 256, 0, stream>>>(Q0, Q1, C0, C1, q2, c2, tkd, tki, out, n1, n2, NCF);
  } else {
    float* wsf = (float*)d_ws;
    int nc = 8;
    while (nc > 1 && (c2n + q2n + (size_t)n1 * nc * KSEL * 2) * 4 > ws_size) nc >>= 1;
    float* c2  = wsf;
    float* q2  = wsf + c2n;
    float* tkd = wsf + c2n + q2n;
    int*   tki = (int*)(wsf + c2n + q2n + (size_t)n1 * nc * KSEL);

    rows_sumsq_kernel<<<(n2 + n1 + 3)/4, 256, 0, stream>>>(C0, Q0, c2, q2, n2, n1);
    const int chunk  = (n2 + nc - 1) / nc;
    const int mtiles = (n1 + MT - 1) / MT;
    (void)hipFuncSetAttribute((const void*)knn_phase1_cvt_kernel,
                              hipFuncAttributeMaxDynamicSharedMemorySize, 163840);
    knn_phase1_cvt_kernel<<<dim3(mtiles, nc), NTH, 163840, stream>>>(
        Q0, C0, q2, c2, tkd, tki, n1, n2, chunk, nc);
    knn_phase2_kernel<<<n1, 256, 0, stream>>>(Q0, Q1, C0, C1, q2, c2, tkd, tki, out, n1, n2, nc);
  }
}

// Round 14
// 472.949 us; speedup vs baseline: 1.1437x; 1.1437x over previous
//
#include <hip/hip_runtime.h>
#include <math.h>

// KNN (L2 top-32) + cosine re-rank, MI355X.
// P0 : fused row sum-of-squares (exact fp32) + fp32->bf16(hi,RTN) table write.
// P1 : 1-pass bf16 MFMA distance GEMM (32x32x16), 64q x 256c tiles, KC=32.
//      Qg=2: each wave computes 64q x 32c -> 6 b128 LDS reads per 4 MFMA
//      (attacks the measured LDS-pipe saturation). Ring-4 C slices (3 in
//      flight, exact vmcnt(6)/4/2/0; c2 reg-double-buffered). Q resident in
//      LDS (staged once, swizzled). Wave-private barrier-free main loop.
//      Epilogue: dl exchange in 2 passes of 32 rows (4 LDS-only barriers).
//      Selection: per-lane top-5 (pure VALU), pivot+compact+rank per chunk.
// P2 : merge 8x32 -> noisy top-64 -> EXACT fp32 rescore -> exact top-32 -> cosine.
// Fallback (small ws): R4's in-kernel-conversion 3-pass kernel (proven).

#define D       512
#define KSEL    32
#define NSELMX  64
#define NCF     8      // chunks == #XCDs
#define TOPL    5
#define CEPS    1e-8f
#define INF     __builtin_inff()

// fast-path phase-1 geometry
#define MTF     64
#define NTF     256
#define KCF     32
#define NTHF    512

// fallback geometry (R4 kernel, unchanged)
#define MT      64
#define NT      512
#define KC      64
#define NTH     512

using s16x8  = __attribute__((ext_vector_type(8)))  short;
using f32x16 = __attribute__((ext_vector_type(16))) float;

__device__ __forceinline__ void async16(const void* g, void* s) {
  __builtin_amdgcn_global_load_lds(
      (const __attribute__((address_space(1))) unsigned int*)g,
      (__attribute__((address_space(3))) unsigned int*)s, 16, 0, 0);
}

// LDS-only barrier (no vmcnt drain)
#define BARL() do { asm volatile("s_waitcnt lgkmcnt(0)" ::: "memory"); \
                    __builtin_amdgcn_s_barrier();                      \
                    asm volatile("" ::: "memory"); } while (0)

// two fp32 -> packed bf16 pair (RTN)
__device__ __forceinline__ unsigned int bfhi2(float x0, float x1) {
  unsigned int u0 = __float_as_uint(x0), u1 = __float_as_uint(x1);
  u0 = (u0 + 0x7fffu + ((u0 >> 16) & 1u)) >> 16;
  u1 = (u1 + 0x7fffu + ((u1 >> 16) & 1u)) & 0xffff0000u;
  return u0 | u1;
}

// ---------------- P0 (fast): fused sumsq + bf16 conversion ----------------
__global__ __launch_bounds__(256) void sumsq_cvt_kernel(
    const float* __restrict__ C, const float* __restrict__ Q,
    float* __restrict__ c2, float* __restrict__ q2,
    unsigned short* __restrict__ Cb, unsigned short* __restrict__ Qb,
    int n2, int n1)
{
  int wid  = threadIdx.x >> 6;
  int lane = threadIdx.x & 63;
  int row  = blockIdx.x * 4 + wid;
  const float* src; float* dst; unsigned short* bdst;
  if (row < n2) { src = C + (size_t)row * D; dst = c2 + row; bdst = Cb + (size_t)row * D; }
  else {
    int r = row - n2; if (r >= n1) return;
    src = Q + (size_t)r * D; dst = q2 + r; bdst = Qb + (size_t)r * D;
  }
  const float4* s4 = (const float4*)src;
  float4 a = s4[2*lane], b = s4[2*lane + 1];
  float s = a.x*a.x + a.y*a.y + a.z*a.z + a.w*a.w
          + b.x*b.x + b.y*b.y + b.z*b.z + b.w*b.w;
  int4 h;
  h.x = (int)bfhi2(a.x, a.y); h.y = (int)bfhi2(a.z, a.w);
  h.z = (int)bfhi2(b.x, b.y); h.w = (int)bfhi2(b.z, b.w);
  *(int4*)(bdst + 8*lane) = h;
  #pragma unroll
  for (int o = 32; o > 0; o >>= 1) s += __shfl_down(s, o, 64);
  if (lane == 0) *dst = s;
}

// ---------------- P0 (fallback): row sum-of-squares only ----------------
__global__ __launch_bounds__(256) void rows_sumsq_kernel(
    const float* __restrict__ C, const float* __restrict__ Q,
    float* __restrict__ c2, float* __restrict__ q2, int n2, int n1)
{
  int wid  = threadIdx.x >> 6;
  int lane = threadIdx.x & 63;
  int row  = blockIdx.x * 4 + wid;
  const float* src; float* dst;
  if (row < n2) { src = C + (size_t)row * D; dst = c2 + row; }
  else { int r = row - n2; if (r >= n1) return; src = Q + (size_t)r * D; dst = q2 + r; }
  const float4* s4 = (const float4*)src;
  float4 a = s4[lane], b = s4[lane + 64];
  float s = a.x*a.x + a.y*a.y + a.z*a.z + a.w*a.w
          + b.x*b.x + b.y*b.y + b.z*b.z + b.w*b.w;
  #pragma unroll
  for (int o = 32; o > 0; o >>= 1) s += __shfl_down(s, o, 64);
  if (lane == 0) *dst = s;
}

// lexicographic max of (d,i) over lanes 0..31 (fallback kernel only)
__device__ inline void worst_reduce(float dIn, int iIn, float& wd, int& wi) {
  float dd = dIn; int ii = iIn;
  #pragma unroll
  for (int o = 1; o <= 16; o <<= 1) {
    float dp = __shfl_xor(dd, o, 64);
    int   ip = __shfl_xor(ii, o, 64);
    bool take = (dp > dd) || (dp == dd && ip > ii);
    dd = take ? dp : dd; ii = take ? ip : ii;
  }
  wd = __shfl(dd, 0, 64); wi = __shfl(ii, 0, 64);
}

// fp32 -> (bf16_hi, bf16_lo) split (fallback kernel only)
__device__ inline void cvt8(const float4 a, const float4 b, int4& hi, int4& lo) {
  float x[8] = {a.x, a.y, a.z, a.w, b.x, b.y, b.z, b.w};
  unsigned int hw[8], lw[8];
  #pragma unroll
  for (int j = 0; j < 8; ++j) {
    unsigned int ux = __float_as_uint(x[j]);
    unsigned int rh = (ux + 0x7fffu + ((ux >> 16) & 1u)) & 0xffff0000u;
    float rl = x[j] - __uint_as_float(rh);
    unsigned int ul = __float_as_uint(rl);
    hw[j] = rh >> 16;
    lw[j] = (ul + 0x7fffu + ((ul >> 16) & 1u)) >> 16;
  }
  hi = make_int4((int)(hw[0]|(hw[1]<<16)), (int)(hw[2]|(hw[3]<<16)),
                 (int)(hw[4]|(hw[5]<<16)), (int)(hw[6]|(hw[7]<<16)));
  lo = make_int4((int)(lw[0]|(lw[1]<<16)), (int)(lw[2]|(lw[3]<<16)),
                 (int)(lw[4]|(lw[5]<<16)), (int)(lw[6]|(lw[7]<<16)));
}

// ---------------- Phase 1 (fast): Qg=2 ring-4 bf16 MFMA ----------------
// LDS (160KB): qs [64][512] swz 64K [0,64K) | ring 4x16K [64K,128K) | dl [32][256] 32K [128K,160K)
// end-of-chunk sel buffer reuses [0,32K): 512 u64/wave.
__global__ __launch_bounds__(NTHF, 2) void knn_phase1_bf_kernel(
    const unsigned short* __restrict__ Qb, const unsigned short* __restrict__ Cb,
    const float* __restrict__ q2g, const float* __restrict__ c2g,
    float* __restrict__ tkd, int* __restrict__ tki,
    int n1, int n2, int chunk, int nc)
{
  extern __shared__ char smem[];
  unsigned short* qs = (unsigned short*)smem;       // [64][512] swizzled
  char* ringb = smem + 65536;                       // 4 x 16KB
  float* dl   = (float*)(smem + 131072);            // [32][256]

  const int tid  = threadIdx.x;
  const int w    = tid >> 6;       // wave 0..7
  const int l    = tid & 63;
  const int l31  = l & 31;
  const int half = l >> 5;
  const int bid     = blockIdx.x;
  const int chunkid = bid & (NCF - 1);   // XCD chunk-affinity
  const int mbase   = (bid >> 3) * MTF;
  const int cbase0  = chunkid * chunk;
  const int cend    = min(cbase0 + chunk, n2);

  // list g (g=0..7): global query row = mbase + (g>>2)*32 + w*4 + (g&3)
  float q2w[8];
  #pragma unroll
  for (int g = 0; g < 8; ++g)
    q2w[g] = q2g[min(mbase + (g>>2)*32 + w*4 + (g&3), n1 - 1)];

  unsigned long long vv[8][TOPL];
  #pragma unroll
  for (int g = 0; g < 8; ++g)
    #pragma unroll
    for (int t = 0; t < TOPL; ++t) vv[g][t] = 0xffffffffffffffffULL;

  // c2 double-buffer (oldest in vm queue -> retired by prologue vmcnt(6))
  float4 c2cur = *(const float4*)(c2g + cbase0 + 4*l);
  float4 c2nxt = c2cur;

  // ---- prologue: stage Q once (row r: phys unit u holds logical u^(r&7)) ----
  #pragma unroll
  for (int g = 0; g < 8; ++g) {
    int rho = w*8 + g;
    int gq  = min(mbase + rho, n1 - 1);
    const unsigned short* src = Qb + (size_t)gq * D + (size_t)((l ^ (rho & 7)) * 8);
    unsigned short* dst = qs + rho * 512;            // wave-uniform base; +lane*16B implicit
    async16(src, dst);
  }

  // C stage: slice s4 = (tile s4>>4, kb s4&15); wave stripe cands w*32+[0,32)
  // slice layout [256 cands][32 k] bf16, unit (16B) u' = u ^ ((cand>>1)&3)
  auto STAGE = [&](int slot, int s4) {
    int t4 = s4 >> 4, kb4 = s4 & 15;
    #pragma unroll
    for (int i = 0; i < 2; ++i) {
      int cl  = w*32 + i*16 + (l >> 2);              // cand within tile
      int gr  = cbase0 + t4*NTF + cl;                // padded Cb: may overrun cend
      int usr = (l & 3) ^ ((cl >> 1) & 3);           // pre-swizzled source unit
      const unsigned short* src = Cb + (size_t)gr * D + kb4*KCF + usr*8;
      unsigned short* dst = (unsigned short*)(ringb + slot*16384) + (w*32 + i*16)*32;
      async16(src, dst);
    }
  };

  f32x16 zf;
  #pragma unroll
  for (int e = 0; e < 16; ++e) zf[e] = 0.f;

  const int nst   = (cend - cbase0 + NTF - 1) / NTF;
  const int total = nst * 16;
  STAGE(0,0); STAGE(1,1); STAGE(2,2); STAGE(3,3);
  // retire c2cur(1) + Q(8) + slice0(2): 17 outstanding -> 6
  asm volatile("s_waitcnt vmcnt(6)" ::: "memory");
  __builtin_amdgcn_s_barrier();                      // all waves' Q visible

  f32x16 acc[2];
  acc[0] = zf; acc[1] = zf;

  for (int nt = 0; nt < nst; ++nt) {
    const int cbase = cbase0 + nt * NTF;

    #pragma unroll
    for (int kb = 0; kb < 16; ++kb) {
      const int s   = nt*16 + kb;
      const int rem = total - 1 - s;
      if (rem > 2)       asm volatile("s_waitcnt vmcnt(6)" ::: "memory");
      else if (rem == 2) asm volatile("s_waitcnt vmcnt(4)" ::: "memory");
      else if (rem == 1) asm volatile("s_waitcnt vmcnt(2)" ::: "memory");
      else               asm volatile("s_waitcnt vmcnt(0)" ::: "memory");

      if (kb == 0 && nt + 1 < nst)   // prefetch next tile's c2
        c2nxt = *(const float4*)(c2g + cbase + NTF + 4*l);

      const unsigned short* cb_ =
          (const unsigned short*)(ringb + (s & 3)*16384) + (w*32 + l31)*32;
      #pragma unroll
      for (int ks = 0; ks < 2; ++ks) {
        // C fragment: cand = w*32+l31, k = kb*32 + ks*16 + half*8 + [0,8)
        int uc = (ks*2 + half) ^ ((l31 >> 1) & 3);
        s16x8 cf = *(const s16x8*)(cb_ + uc*8);
        #pragma unroll
        for (int qg = 0; qg < 2; ++qg) {
          // Q fragment: row = qg*32+l31, k-unit = kb*4 + ks*2 + half
          int uq = (kb*4 + ks*2 + half) ^ (l31 & 7);
          s16x8 qf = *(const s16x8*)(qs + (qg*32 + l31)*512 + uq*8);
          acc[qg] = __builtin_amdgcn_mfma_f32_32x32x16_bf16(qf, cf, acc[qg], 0, 0, 0);
        }
      }
      if (s + 4 < total) {
        asm volatile("s_waitcnt lgkmcnt(0)" ::: "memory");   // my reads of slot done
        STAGE(s & 3, s + 4);
      }
    }

    // ---- tile epilogue: 2 passes of 32 rows (dl exchange + filter) ----
    #pragma unroll
    for (int p = 0; p < 2; ++p) {
      #pragma unroll
      for (int r = 0; r < 16; ++r) {
        int rr = (r & 3) + 8*(r >> 2) + 4*half;      // verified 32x32 C layout
        dl[rr*NTF + w*32 + l31] = acc[p][r];         // raw dot, 2-way (free) banks
      }
      BARL();
      {
        float c2s[4] = {c2cur.x, c2cur.y, c2cur.z, c2cur.w};
        #pragma unroll
        for (int j = 0; j < 4; ++j) {
          const int g = p*4 + j;
          const float q2u = q2w[g];
          float4 sv4 = *((const float4*)(dl + (w*4 + j)*NTF) + l);
          float svs[4] = {sv4.x, sv4.y, sv4.z, sv4.w};
          #pragma unroll
          for (int jj = 0; jj < 4; ++jj) {
            int ci = cbase + 4*l + jj;
            if (ci < cend) {
              float d2v = fmaxf(q2u + c2s[jj] - 2.f*svs[jj], 0.f);
              unsigned long long e =
                  ((unsigned long long)__float_as_uint(d2v) << 32) | (unsigned int)ci;
              if (e < vv[g][TOPL-1]) {
                vv[g][TOPL-1] = e;
                #pragma unroll
                for (int t = TOPL-1; t > 0; --t) {
                  unsigned long long lo = vv[g][t-1] < vv[g][t] ? vv[g][t-1] : vv[g][t];
                  unsigned long long hi = vv[g][t-1] < vv[g][t] ? vv[g][t]   : vv[g][t-1];
                  vv[g][t-1] = lo; vv[g][t] = hi;
                }
              }
            }
          }
        }
      }
      BARL();
      acc[p] = zf;
    }
    c2cur = c2nxt;
  }

  // ---- end-of-chunk selection: pivot + compact + rank (per wave, 8 lists) ----
  unsigned long long* sel = (unsigned long long*)smem + (size_t)w * 512;
  const unsigned long long mlt = (l == 0) ? 0ull : ((~0ull) >> (64 - l));
  __syncthreads();   // everyone past main loop before qs reuse
  #pragma unroll
  for (int g = 0; g < 8; ++g) {
    unsigned int pk = (unsigned int)(vv[g][0] >> 32);
    #pragma unroll
    for (int o = 1; o < 64; o <<= 1) {
      unsigned int other = (unsigned int)__shfl_xor((int)pk, o, 64);
      pk = (other > pk) ? other : pk;
    }
    int cnt = 0;
    #pragma unroll
    for (int t = 0; t < TOPL; ++t) cnt += ((unsigned int)(vv[g][t] >> 32) <= pk) ? 1 : 0;
    unsigned long long b0 = __ballot(cnt & 1);
    unsigned long long b1 = __ballot(cnt & 2);
    unsigned long long b2 = __ballot(cnt & 4);
    int pre = __popcll(b0 & mlt) + 2*__popcll(b1 & mlt) + 4*__popcll(b2 & mlt);
    int Ns  = __popcll(b0) + 2*__popcll(b1) + 4*__popcll(b2);
    #pragma unroll
    for (int t = 0; t < TOPL; ++t)
      if (t < cnt) sel[pre + t] = vv[g][t];
    asm volatile("s_waitcnt lgkmcnt(0)" ::: "memory");
    __builtin_amdgcn_sched_barrier(0);
    int rk[TOPL];
    #pragma unroll
    for (int t = 0; t < TOPL; ++t) rk[t] = 0;
    for (int j = 0; j < Ns; ++j) {
      unsigned long long e = sel[j];
      #pragma unroll
      for (int t = 0; t < TOPL; ++t) rk[t] += (e < vv[g][t]) ? 1 : 0;
    }
    int gq = mbase + (g>>2)*32 + w*4 + (g&3);
    if (gq < n1) {
      #pragma unroll
      for (int t = 0; t < TOPL; ++t)
        if (t < cnt && rk[t] < KSEL) {
          size_t o = ((size_t)gq * nc + chunkid) * KSEL + rk[t];
          tkd[o] = __uint_as_float((unsigned int)(vv[g][t] >> 32));
          tki[o] = (int)(unsigned int)(vv[g][t] & 0xffffffffu);
        }
    }
  }
}

// ---------------- Phase 1 (fallback): R4 in-kernel-conversion 3-pass ----------------
__global__ __launch_bounds__(NTH) void knn_phase1_cvt_kernel(
    const float* __restrict__ Q, const float* __restrict__ C,
    const float* __restrict__ q2g, const float* __restrict__ c2g,
    float* __restrict__ tkd, int* __restrict__ tki,
    int n1, int n2, int chunk, int nc)
{
  extern __shared__ char smem[];
  unsigned short* qh = (unsigned short*)smem;
  unsigned short* ql = qh + 64*64;
  unsigned short* ch = ql + 64*64;
  unsigned short* cl = ch + 512*64;
  float* dl = (float*)(smem + 147456);

  const int tid  = threadIdx.x;
  const int w    = tid >> 6;
  const int l    = tid & 63;
  const int l31  = l & 31;
  const int half = l >> 5;
  const int mbase   = blockIdx.x * MT;
  const int chunkid = blockIdx.y;
  const int cbase0  = chunkid * chunk;
  const int cend    = min(cbase0 + chunk, n2);

  float q2w[8];
  #pragma unroll
  for (int g = 0; g < 8; ++g) q2w[g] = q2g[min(mbase + g*8 + w, n1 - 1)];

  float listd[8]; int listi[8]; float wd4[8]; int wi4[8];
  #pragma unroll
  for (int g = 0; g < 8; ++g) { listd[g]=INF; listi[g]=0x7fffffff; wd4[g]=INF; wi4[g]=0x7fffffff; }

  const int srow = tid >> 3;
  const int sk8  = (tid & 7) * 8;
  const int su   = (tid & 7);

  float4 cva[8][2], qva[2];
  auto LOADR = [&](int kb, int cb) {
    {
      int gr = min(mbase + srow, n1 - 1);
      const float4* p = (const float4*)(Q + (size_t)gr * D + kb*KC + sk8);
      qva[0] = p[0]; qva[1] = p[1];
    }
    #pragma unroll
    for (int r = 0; r < 8; ++r) {
      int gn = cb + srow + 64*r;
      if (gn < cend) {
        const float4* p = (const float4*)(C + (size_t)gn * D + kb*KC + sk8);
        cva[r][0] = p[0]; cva[r][1] = p[1];
      } else {
        cva[r][0] = make_float4(0.f,0.f,0.f,0.f);
        cva[r][1] = make_float4(0.f,0.f,0.f,0.f);
      }
    }
  };
  auto STORE = [&]() {
    int4 hi, lo;
    {
      int idx = srow*64 + (su ^ (srow & 7))*8;
      cvt8(qva[0], qva[1], hi, lo);
      *(int4*)(qh + idx) = hi; *(int4*)(ql + idx) = lo;
    }
    #pragma unroll
    for (int r = 0; r < 8; ++r) {
      int row = srow + 64*r;
      int idx = row*64 + (su ^ (row & 7))*8;
      cvt8(cva[r][0], cva[r][1], hi, lo);
      *(int4*)(ch + idx) = hi; *(int4*)(cl + idx) = lo;
    }
  };

  f32x16 zf;
  #pragma unroll
  for (int e = 0; e < 16; ++e) zf[e] = 0.f;

  const int nsteps = (cend - cbase0 + NT - 1) / NT;
  LOADR(0, cbase0);

  for (int nt = 0; nt < nsteps; ++nt) {
    const int cbase = cbase0 + nt * NT;
    f32x16 acc[2][2];
    #pragma unroll
    for (int rt = 0; rt < 2; ++rt)
      #pragma unroll
      for (int ct = 0; ct < 2; ++ct) acc[rt][ct] = zf;

    for (int kb = 0; kb < D/KC; ++kb) {
      __syncthreads();
      STORE();
      __syncthreads();
      if (kb + 1 < D/KC)        LOADR(kb + 1, cbase);
      else if (nt + 1 < nsteps) LOADR(0, cbase + NT);

      #pragma unroll
      for (int ks = 0; ks < 4; ++ks) {
        const int u = 2*ks + half;
        s16x8 qf[2][2], cf[2][2];
        #pragma unroll
        for (int rt = 0; rt < 2; ++rt) {
          int r = rt*32 + l31;
          int idx = r*64 + (u ^ (r & 7))*8;
          qf[rt][0] = *(const s16x8*)(qh + idx);
          qf[rt][1] = *(const s16x8*)(ql + idx);
        }
        #pragma unroll
        for (int ct = 0; ct < 2; ++ct) {
          int c = w*64 + ct*32 + l31;
          int idx = c*64 + (u ^ (c & 7))*8;
          cf[ct][0] = *(const s16x8*)(ch + idx);
          cf[ct][1] = *(const s16x8*)(cl + idx);
        }
        #pragma unroll
        for (int rt = 0; rt < 2; ++rt)
          #pragma unroll
          for (int ct = 0; ct < 2; ++ct) {
            acc[rt][ct] = __builtin_amdgcn_mfma_f32_32x32x16_bf16(qf[rt][0], cf[ct][0], acc[rt][ct], 0, 0, 0);
            acc[rt][ct] = __builtin_amdgcn_mfma_f32_32x32x16_bf16(qf[rt][0], cf[ct][1], acc[rt][ct], 0, 0, 0);
            acc[rt][ct] = __builtin_amdgcn_mfma_f32_32x32x16_bf16(qf[rt][1], cf[ct][0], acc[rt][ct], 0, 0, 0);
          }
      }
    }

    float c2v[2]; int vld[2];
    #pragma unroll
    for (int ct = 0; ct < 2; ++ct) {
      int gc = cbase + w*64 + ct*32 + l31;
      vld[ct] = (gc < cend);
      c2v[ct] = vld[ct] ? c2g[gc] : 0.f;
    }
    #pragma unroll
    for (int g = 0; g < 8; ++g) {
      const int rt = g >> 2, qq = g & 3;
      #pragma unroll
      for (int jj = 0; jj < 4; ++jj)
        #pragma unroll
        for (int ct = 0; ct < 2; ++ct) {
          float a = acc[rt][ct][4*qq + jj];
          float s = c2v[ct] - 2.f * a;
          dl[(4*half + jj)*512 + w*64 + ct*32 + l31] = vld[ct] ? s : INF;
        }
      __syncthreads();
      const float q2u = q2w[g];
      #pragma unroll
      for (int j2 = 0; j2 < 8; ++j2) {
        float sv = dl[w*512 + l + 64*j2];
        float dv = sqrtf(fmaxf(q2u + sv, 0.f));
        unsigned long long mask = __ballot(dv < wd4[g]);
        while (mask) {
          int L = __ffsll(mask) - 1; mask &= mask - 1;
          float dnew = __shfl(dv, L, 64);
          int ci = cbase + 64*j2 + L;
          if ((dnew < wd4[g]) || (dnew == wd4[g] && ci < wi4[g])) {
            bool isw = (l < 32) && (listd[g] == wd4[g]) && (listi[g] == wi4[g]);
            int wl = __ffsll(__ballot(isw)) - 1;
            if (l == wl) { listd[g] = dnew; listi[g] = ci; }
            worst_reduce((l < 32) ? listd[g] : -1.f,
                         (l < 32) ? listi[g] : -1, wd4[g], wi4[g]);
          }
        }
      }
      __syncthreads();
    }
  }

  #pragma unroll
  for (int g = 0; g < 8; ++g) {
    int gq = mbase + g*8 + w;
    float d = listd[g]; int i = listi[g];
    int rank = 0;
    #pragma unroll
    for (int j = 0; j < KSEL; ++j) {
      float dj = __shfl(listd[g], j, 64);
      int   ij = __shfl(listi[g], j, 64);
      rank += (dj < d) || (dj == d && ij < i);
    }
    if (l < 32 && gq < n1) {
      size_t o = ((size_t)gq * nc + chunkid) * KSEL + rank;
      tkd[o] = d; tki[o] = i;
    }
  }
}

// ---------------- Phase 2: merge + exact rescore + cosine ----------------
__global__ __launch_bounds__(256) void knn_phase2_kernel(
    const float* __restrict__ Q0, const float* __restrict__ Q1,
    const float* __restrict__ C0, const float* __restrict__ C1,
    const float* __restrict__ q2g, const float* __restrict__ c2g,
    const float* __restrict__ tkd, const int* __restrict__ tki,
    float* __restrict__ out, int n1, int n2, int nc)
{
  __shared__ float q0s[D], q1s[D];
  __shared__ float pd[256]; __shared__ int pi[256];
  __shared__ float nd[NSELMX]; __shared__ int ni[NSELMX];
  __shared__ float de[NSELMX];
  __shared__ int   fi[KSEL];
  __shared__ float cosj[KSEL];
  __shared__ float red0[4], red1[4], qn[2];

  const int q = blockIdx.x, tid = threadIdx.x;
  const int npool = nc * KSEL;
  const int nsel  = (NSELMX < npool) ? NSELMX : npool;

  if (tid < 128) ((float4*)q0s)[tid] = ((const float4*)(Q0 + (size_t)q*D))[tid];
  else           ((float4*)q1s)[tid-128] = ((const float4*)(Q1 + (size_t)q*D))[tid-128];
  if (tid < npool) { pd[tid] = tkd[(size_t)q*npool + tid]; pi[tid] = tki[(size_t)q*npool + tid]; }
  __syncthreads();

  float a0 = q0s[tid], b0 = q0s[tid+256], a1 = q1s[tid], b1 = q1s[tid+256];
  float s0 = a0*a0 + b0*b0, s1 = a1*a1 + b1*b1;
  #pragma unroll
  for (int o = 32; o > 0; o >>= 1) { s0 += __shfl_down(s0, o, 64); s1 += __shfl_down(s1, o, 64); }
  int lane = tid & 63, wid = tid >> 6;
  if (lane == 0) { red0[wid] = s0; red1[wid] = s1; }

  if (tid < npool) {
    float dm = pd[tid]; int im = pi[tid]; int rank = 0;
    for (int j = 0; j < npool; ++j) {
      float dj = pd[j]; int ij = pi[j];
      rank += (dj < dm) || (dj == dm && ij < im);
    }
    if (rank < nsel) { nd[rank] = dm; ni[rank] = im; }
  }
  __syncthreads();
  if (tid == 0) {
    qn[0] = fmaxf(sqrtf(red0[0]+red0[1]+red0[2]+red0[3]), CEPS);
    qn[1] = fmaxf(sqrtf(red1[0]+red1[1]+red1[2]+red1[3]), CEPS);
  }

  const float q2q = q2g[q];
  const int ll = tid & 7;
  for (int base = 0; base < NSELMX; base += 32) {
    int g = base + (tid >> 3);
    if (g < nsel) {
      int ix = ni[g];
      bool okx = (ix >= 0 && ix < n2);
      int ixc = okx ? ix : 0;
      const float4* r0  = (const float4*)(C0 + (size_t)ixc * D);
      const float4* q04 = (const float4*)q0s;
      float dot = 0.f;
      #pragma unroll
      for (int r = 0; r < 16; ++r) {
        float4 v = r0[r*8 + ll], u = q04[r*8 + ll];
        dot = fmaf(v.x,u.x, fmaf(v.y,u.y, fmaf(v.z,u.z, fmaf(v.w,u.w, dot))));
      }
      #pragma unroll
      for (int o = 4; o > 0; o >>= 1) dot += __shfl_xor(dot, o, 64);
      if (ll == 0) de[g] = okx ? sqrtf(fmaxf(q2q + c2g[ixc] - 2.f*dot, 0.f)) : INF;
    }
  }
  __syncthreads();

  if (tid < nsel) {
    float dm = de[tid]; int im = ni[tid]; int rank = 0;
    for (int j = 0; j < nsel; ++j) {
      float dj = de[j]; int ij = ni[j];
      rank += (dj < dm) || (dj == dm && ij < im);
    }
    if (rank < KSEL) fi[rank] = im;
  }
  __syncthreads();

  const int g = tid >> 3;
  int ix = fi[g];
  ix = (ix >= 0 && ix < n2) ? ix : 0;
  const float4* r0  = (const float4*)(C0 + (size_t)ix * D);
  const float4* r1  = (const float4*)(C1 + (size_t)ix * D);
  const float4* q04 = (const float4*)q0s;
  const float4* q14 = (const float4*)q1s;
  float dot0 = 0.f, nn0 = 0.f, dot1 = 0.f, nn1 = 0.f;
  #pragma unroll
  for (int r = 0; r < 16; ++r) {
    int e4 = r*8 + ll;
    float4 v0 = r0[e4], qv0 = q04[e4];
    dot0 = fmaf(v0.x,qv0.x, fmaf(v0.y,qv0.y, fmaf(v0.z,qv0.z, fmaf(v0.w,qv0.w, dot0))));
    nn0  = fmaf(v0.x,v0.x,  fmaf(v0.y,v0.y,  fmaf(v0.z,v0.z,  fmaf(v0.w,v0.w,  nn0))));
    float4 v1 = r1[e4], qv1 = q14[e4];
    dot1 = fmaf(v1.x,qv1.x, fmaf(v1.y,qv1.y, fmaf(v1.z,qv1.z, fmaf(v1.w,qv1.w, dot1))));
    nn1  = fmaf(v1.x,v1.x,  fmaf(v1.y,v1.y,  fmaf(v1.z,v1.z,  fmaf(v1.w,v1.w,  nn1))));
  }
  #pragma unroll
  for (int o = 4; o > 0; o >>= 1) {
    dot0 += __shfl_xor(dot0, o, 64); nn0 += __shfl_xor(nn0, o, 64);
    dot1 += __shfl_xor(dot1, o, 64); nn1 += __shfl_xor(nn1, o, 64);
  }
  if (ll == 0) {
    float c0 = dot0 / (fmaxf(sqrtf(nn0), CEPS) * qn[0]);
    float c1 = dot1 / (fmaxf(sqrtf(nn1), CEPS) * qn[1]);
    float cv = (c0 > c1) ? c0 : c1;
    out[(size_t)q * KSEL + g] = cv;
    cosj[g] = cv;
  }
  __syncthreads();
  if (tid == 0) {
    float s = 0.f;
    #pragma unroll
    for (int j = 0; j < KSEL; ++j) s += cosj[j];
    out[(size_t)n1 * KSEL + q] = s * (1.f / KSEL);
  }
}

// ---------------- launch ----------------
extern "C" void kernel_launch(void* const* d_in, const int* in_sizes, int n_in,
                              void* d_out, int out_size, void* d_ws, size_t ws_size,
                              hipStream_t stream)
{
  const float* Q0 = (const float*)d_in[0];
  const float* Q1 = (const float*)d_in[1];
  const float* C0 = (const float*)d_in[2];
  const float* C1 = (const float*)d_in[3];
  const int n1 = in_sizes[0] / D;   // 2048
  const int n2 = in_sizes[2] / D;   // 50000
  float* out = (float*)d_out;
  if (n1 <= 0 || n2 <= 0) return;

  char* wsb = (char*)d_ws;
  size_t c2n = ((size_t)n2 + 127) & ~(size_t)127;
  size_t q2n = ((size_t)n1 + 127) & ~(size_t)127;

  size_t off_c2  = 0;
  size_t off_q2  = off_c2 + c2n*4;
  size_t off_tkd = off_q2 + q2n*4;
  size_t off_tki = off_tkd + (size_t)n1*NCF*KSEL*4;
  size_t off_cb  = (off_tki + (size_t)n1*NCF*KSEL*4 + 255) & ~(size_t)255;
  size_t off_qb  = off_cb + ((size_t)n2 + 512)*D*2;
  size_t need    = off_qb + (size_t)n1*D*2;
  bool fast = (ws_size >= need);

  if (fast) {
    float* c2  = (float*)(wsb + off_c2);
    float* q2  = (float*)(wsb + off_q2);
    float* tkd = (float*)(wsb + off_tkd);
    int*   tki = (int*)(wsb + off_tki);
    unsigned short* Cb = (unsigned short*)(wsb + off_cb);
    unsigned short* Qb = (unsigned short*)(wsb + off_qb);

    sumsq_cvt_kernel<<<(n2 + n1 + 3)/4, 256, 0, stream>>>(C0, Q0, c2, q2, Cb, Qb, n2, n1);

    const int chunk  = (n2 + NCF - 1) / NCF;
    const int mtiles = (n1 + MTF - 1) / MTF;
    (void)hipFuncSetAttribute((const void*)knn_phase1_bf_kernel,
                              hipFuncAttributeMaxDynamicSharedMemorySize, 163840);
    knn_phase1_bf_kernel<<<mtiles * NCF, NTHF, 163840, stream>>>(
        Qb, Cb, q2, c2, tkd, tki, n1, n2, chunk, NCF);
    knn_phase2_kernel<<<n1, 256, 0, stream>>>(Q0, Q1, C0, C1, q2, c2, tkd, tki, out, n1, n2, NCF);
  } else {
    float* wsf = (float*)d_ws;
    int nc = 8;
    while (nc > 1 && (c2n + q2n + (size_t)n1 * nc * KSEL * 2) * 4 > ws_size) nc >>= 1;
    float* c2  = wsf;
    float* q2  = wsf + c2n;
    float* tkd = wsf + c2n + q2n;
    int*   tki = (int*)(wsf + c2n + q2n + (size_t)n1 * nc * KSEL);

    rows_sumsq_kernel<<<(n2 + n1 + 3)/4, 256, 0, stream>>>(C0, Q0, c2, q2, n2, n1);
    const int chunk  = (n2 + nc - 1) / nc;
    const int mtiles = (n1 + MT - 1) / MT;
    (void)hipFuncSetAttribute((const void*)knn_phase1_cvt_kernel,
                              hipFuncAttributeMaxDynamicSharedMemorySize, 163840);
    knn_phase1_cvt_kernel<<<dim3(mtiles, nc), NTH, 163840, stream>>>(
        Q0, C0, q2, c2, tkd, tki, n1, n2, chunk, nc);
    knn_phase2_kernel<<<n1, 256, 0, stream>>>(Q0, Q1, C0, C1, q2, c2, tkd, tki, out, n1, n2, nc);
  }
}